// Round 5
// baseline (43.519 us; speedup 1.0000x reference)
//
#include <hip/hip_runtime.h>

#define NST 10
#define NLBL 50
#define BATCH 256
#define TLEN 1024
#define TPB 512
#define HALO 8
#define ROWS (TPB + 2*HALO)   // 528
#define EPAD 13
#define PRPAD 13
#define SC 1.0e15f
#define LN2F 0.69314718055994531f

__global__ __launch_bounds__(256, 2) void k_all(const int* __restrict__ sent,
                                                const float* __restrict__ W,
                                                const float* __restrict__ trans,
                                                const float* __restrict__ outw,
                                                float* __restrict__ out) {
    __shared__ alignas(16) float Elds[ROWS][EPAD];   // 27.5 KB
    __shared__ alignas(16) float prl[TPB][PRPAD];    // 26.6 KB
    __shared__ alignas(16) float Tl[112];
    __shared__ alignas(16) float Ttl[112];
    __shared__ alignas(16) float Ol[NST][56];

    const int tid = threadIdx.x;
    const int b   = (int)blockIdx.x >> 1;
    const int tb  = ((int)blockIdx.x & 1) * TPB;

    // ---- parameter prep (redundant per block; cheap) ----
    if (tid < NST) {
        float r[NST]; float m = -1e30f, s = 0.f;
        #pragma unroll
        for (int j = 0; j < NST; ++j) { r[j] = trans[tid*NST + j]; m = fmaxf(m, r[j]); }
        #pragma unroll
        for (int j = 0; j < NST; ++j) { r[j] = __expf(r[j] - m); s += r[j]; }
        float inv = 1.f / s;
        #pragma unroll
        for (int j = 0; j < NST; ++j) { Tl[tid*NST + j] = r[j]*inv; Ttl[j*NST + tid] = r[j]*inv; }
    } else if (tid >= 32 && tid < 32 + NST) {
        const int i = tid - 32;
        float m = -1e30f, s = 0.f; float r[NLBL];
        for (int l = 0; l < NLBL; ++l) { r[l] = outw[i*NLBL + l]; m = fmaxf(m, r[l]); }
        for (int l = 0; l < NLBL; ++l) { r[l] = __expf(r[l] - m); s += r[l]; }
        float inv = 1.f / s;
        for (int l = 0; l < NLBL; ++l) Ol[i][l] = r[l]*inv;
        for (int l = NLBL; l < 56; ++l) Ol[i][l] = 0.f;
    }

    // ---- emission staging: gather W[tok], softmax, -> LDS ----
    const int* sb = sent + b*TLEN;
    for (int r = tid; r < ROWS; r += 256) {
        int p  = tb - HALO + r;
        int pc = min(max(p, 0), TLEN-1);
        int tok = sb[pc];
        const float2* w2 = reinterpret_cast<const float2*>(W + (size_t)tok*NST);
        float2 q0=w2[0], q1=w2[1], q2=w2[2], q3=w2[3], q4=w2[4];
        float e[10] = {q0.x,q0.y,q1.x,q1.y,q2.x,q2.y,q3.x,q3.y,q4.x,q4.y};
        float m = e[0];
        #pragma unroll
        for (int j=1;j<10;++j) m = fmaxf(m, e[j]);
        float s = 0.f;
        #pragma unroll
        for (int j=0;j<10;++j) { e[j] = __expf(e[j]-m); s += e[j]; }
        float inv = 1.f/s;
        #pragma unroll
        for (int j=0;j<10;++j) Elds[r][j] = e[j]*inv;
    }
    __syncthreads();

    const int t0  = tb + 2*tid;     // this thread's chunk = {t0, t0+1}
    const int lr0 = 2*tid;          // LDS row of global position t0-HALO

    float vT[100];
    #pragma unroll
    for (int k=0;k<100;++k) vT[k] = Tl[k];

    // ---- forward: 9 steps from t0-HALO, keep alpha(t0), alpha(t0+1) ----
    float alpha[10], a0s[10], a1s[10];
    #pragma unroll
    for (int s=0;s<10;++s) alpha[s] = Elds[lr0][s] * SC;

    #pragma unroll
    for (int i=1;i<=HALO+1;++i) {
        const int p = t0 - HALO + i;
        float an[10];
        #pragma unroll
        for (int s=0;s<10;++s) {
            float acc = 0.f;
            #pragma unroll
            for (int j=0;j<10;++j) acc = fmaf(vT[s*10+j], alpha[j], acc);
            an[s] = acc * Elds[lr0+i][s];
        }
        const bool upd = (p >= 1);
        #pragma unroll
        for (int s=0;s<10;++s) alpha[s] = upd ? an[s] : alpha[s];
        if (i == HALO) {
            #pragma unroll
            for (int s=0;s<10;++s) a0s[s] = alpha[s];
        }
    }
    #pragma unroll
    for (int s=0;s<10;++s) a1s[s] = alpha[s];

    // ---- backward: 9 steps from t0+HALO+1 down to t0; fuse posterior ----
    #pragma unroll
    for (int k=0;k<100;++k) vT[k] = Ttl[k];   // now holds T^T

    float g[10];
    const int lre = 2*tid + 2*HALO + 1;       // LDS row of t0+HALO+1 (clamped data)
    #pragma unroll
    for (int s=0;s<10;++s) g[s] = Elds[lre][s] * SC;

    #pragma unroll
    for (int i=1;i<=HALO+1;++i) {
        const int p = t0 + HALO + 1 - i;
        float u[10];
        #pragma unroll
        for (int s=0;s<10;++s) {
            float acc = 0.f;
            #pragma unroll
            for (int j=0;j<10;++j) acc = fmaf(vT[s*10+j], g[j], acc);
            u[s] = acc;
        }
        const bool last = (p == TLEN-1);
        #pragma unroll
        for (int s=0;s<10;++s) u[s] = last ? SC : u[s];
        if (i == HALO) {          // p == t0+1
            float sum = 0.f; float pr[10];
            #pragma unroll
            for (int s=0;s<10;++s) { pr[s] = a1s[s]*u[s]; sum += pr[s]; }
            #pragma unroll
            for (int s=0;s<10;++s) prl[2*tid+1][s] = pr[s];
            prl[2*tid+1][10] = __log2f(sum);
        }
        if (i == HALO+1) {        // p == t0
            float sum = 0.f; float pr[10];
            #pragma unroll
            for (int s=0;s<10;++s) { pr[s] = a0s[s]*u[s]; sum += pr[s]; }
            #pragma unroll
            for (int s=0;s<10;++s) prl[2*tid][s] = pr[s];
            prl[2*tid][10] = __log2f(sum);
        }
        const bool keep = (p > TLEN-1);
        #pragma unroll
        for (int s=0;s<10;++s) {
            float gn = Elds[lre - i][s] * u[s];
            g[s] = keep ? g[s] : gn;
        }
    }
    __syncthreads();

    // ---- combine: out[t][l] = (log2(dot(pr, O[:,l])) - log2(sum pr)) * ln2 ----
    const int lg = tid & 7;
    const int tq = tid >> 3;
    const int lb = lg * 7;                    // labels lb..lb+6 (masked at 50)
    float vO[10][7];
    #pragma unroll
    for (int s=0;s<10;++s)
        #pragma unroll
        for (int k=0;k<7;++k) vO[s][k] = Ol[s][lb+k];

    float* ob = out + ((size_t)b*TLEN + tb)*NLBL;
    for (int it=0; it<16; ++it) {
        const int t = tq + 32*it;
        float pv[10];
        #pragma unroll
        for (int s=0;s<10;++s) pv[s] = prl[t][s];
        const float ls = prl[t][10];
        float* orow = ob + t*NLBL + lb;
        #pragma unroll
        for (int k=0;k<7;++k) {
            float d = 0.f;
            #pragma unroll
            for (int s=0;s<10;++s) d = fmaf(pv[s], vO[s][k], d);
            float v = (__log2f(d) - ls) * LN2F;
            if (lb + k < NLBL) orow[k] = v;
        }
    }
}

extern "C" void kernel_launch(void* const* d_in, const int* in_sizes, int n_in,
                              void* d_out, int out_size, void* d_ws, size_t ws_size,
                              hipStream_t stream) {
    const int*   sent  = (const int*)d_in[0];
    const float* W     = (const float*)d_in[1];
    const float* trans = (const float*)d_in[2];
    const float* outw  = (const float*)d_in[3];
    float* out = (float*)d_out;

    hipLaunchKernelGGL(k_all, dim3(BATCH * (TLEN / TPB)), dim3(256), 0, stream,
                       sent, W, trans, outw, out);
}

// Round 6
// 43.413 us; speedup vs baseline: 1.0025x; 1.0025x over previous
//
#include <hip/hip_runtime.h>

#define NST 10
#define NLBL 50
#define BATCH 256
#define TLEN 1024
#define TPB 512
#define HALO 8
#define ROWS (TPB + 2*HALO)   // 528
#define EPAD 13
#define PRPAD 13
#define SC 1.0e15f
#define LN2F 0.69314718055994531f

__global__ __launch_bounds__(256, 2) void k_all(const int* __restrict__ sent,
                                                const float* __restrict__ W,
                                                const float* __restrict__ trans,
                                                const float* __restrict__ outw,
                                                float* __restrict__ out) {
    __shared__ alignas(16) float Elds[ROWS][EPAD];   // 27.5 KB (reused as combine stage)
    __shared__ alignas(16) float prl[TPB][PRPAD];    // 26.6 KB
    __shared__ alignas(16) float Tl[112];
    __shared__ alignas(16) float Ttl[112];
    __shared__ alignas(16) float Ol[NST][56];

    const int tid = threadIdx.x;
    const int b   = (int)blockIdx.x >> 1;
    const int tb  = ((int)blockIdx.x & 1) * TPB;

    // ---- parameter prep (redundant per block; cheap) ----
    if (tid < NST) {
        float r[NST]; float m = -1e30f, s = 0.f;
        #pragma unroll
        for (int j = 0; j < NST; ++j) { r[j] = trans[tid*NST + j]; m = fmaxf(m, r[j]); }
        #pragma unroll
        for (int j = 0; j < NST; ++j) { r[j] = __expf(r[j] - m); s += r[j]; }
        float inv = 1.f / s;
        #pragma unroll
        for (int j = 0; j < NST; ++j) { Tl[tid*NST + j] = r[j]*inv; Ttl[j*NST + tid] = r[j]*inv; }
    } else if (tid >= 32 && tid < 32 + NST) {
        const int i = tid - 32;
        float m = -1e30f, s = 0.f; float r[NLBL];
        for (int l = 0; l < NLBL; ++l) { r[l] = outw[i*NLBL + l]; m = fmaxf(m, r[l]); }
        for (int l = 0; l < NLBL; ++l) { r[l] = __expf(r[l] - m); s += r[l]; }
        float inv = 1.f / s;
        for (int l = 0; l < NLBL; ++l) Ol[i][l] = r[l]*inv;
        for (int l = NLBL; l < 56; ++l) Ol[i][l] = 0.f;
    }

    // ---- emission staging: gather W[tok], softmax, -> LDS ----
    const int* sb = sent + b*TLEN;
    for (int r = tid; r < ROWS; r += 256) {
        int p  = tb - HALO + r;
        int pc = min(max(p, 0), TLEN-1);
        int tok = sb[pc];
        const float2* w2 = reinterpret_cast<const float2*>(W + (size_t)tok*NST);
        float2 q0=w2[0], q1=w2[1], q2=w2[2], q3=w2[3], q4=w2[4];
        float e[10] = {q0.x,q0.y,q1.x,q1.y,q2.x,q2.y,q3.x,q3.y,q4.x,q4.y};
        float m = e[0];
        #pragma unroll
        for (int j=1;j<10;++j) m = fmaxf(m, e[j]);
        float s = 0.f;
        #pragma unroll
        for (int j=0;j<10;++j) { e[j] = __expf(e[j]-m); s += e[j]; }
        float inv = 1.f/s;
        #pragma unroll
        for (int j=0;j<10;++j) Elds[r][j] = e[j]*inv;
    }
    __syncthreads();

    const int t0  = tb + 2*tid;     // this thread's chunk = {t0, t0+1}
    const int lr0 = 2*tid;          // LDS row of global position t0-HALO

    float vT[100];
    #pragma unroll
    for (int k=0;k<100;++k) vT[k] = Tl[k];

    // ---- forward: steps from t0-HALO, keep alpha(t0), alpha(t0+1) ----
    float alpha[10], a0s[10], a1s[10];
    #pragma unroll
    for (int s=0;s<10;++s) alpha[s] = Elds[lr0][s] * SC;

    #pragma unroll
    for (int i=1;i<=HALO+1;++i) {
        const int p = t0 - HALO + i;
        float an[10];
        #pragma unroll
        for (int s=0;s<10;++s) {
            float acc = 0.f;
            #pragma unroll
            for (int j=0;j<10;++j) acc = fmaf(vT[s*10+j], alpha[j], acc);
            an[s] = acc * Elds[lr0+i][s];
        }
        const bool upd = (p >= 1);
        #pragma unroll
        for (int s=0;s<10;++s) alpha[s] = upd ? an[s] : alpha[s];
        if (i == HALO) {
            #pragma unroll
            for (int s=0;s<10;++s) a0s[s] = alpha[s];
        }
    }
    #pragma unroll
    for (int s=0;s<10;++s) a1s[s] = alpha[s];

    // ---- backward: steps from t0+HALO+1 down to t0; fuse posterior ----
    #pragma unroll
    for (int k=0;k<100;++k) vT[k] = Ttl[k];   // now holds T^T

    float g[10];
    const int lre = 2*tid + 2*HALO + 1;       // LDS row of t0+HALO+1 (clamped data)
    #pragma unroll
    for (int s=0;s<10;++s) g[s] = Elds[lre][s] * SC;

    #pragma unroll
    for (int i=1;i<=HALO+1;++i) {
        const int p = t0 + HALO + 1 - i;
        float u[10];
        #pragma unroll
        for (int s=0;s<10;++s) {
            float acc = 0.f;
            #pragma unroll
            for (int j=0;j<10;++j) acc = fmaf(vT[s*10+j], g[j], acc);
            u[s] = acc;
        }
        const bool last = (p == TLEN-1);
        #pragma unroll
        for (int s=0;s<10;++s) u[s] = last ? SC : u[s];
        if (i == HALO) {          // p == t0+1
            float sum = 0.f; float pr[10];
            #pragma unroll
            for (int s=0;s<10;++s) { pr[s] = a1s[s]*u[s]; sum += pr[s]; }
            #pragma unroll
            for (int s=0;s<10;++s) prl[2*tid+1][s] = pr[s];
            prl[2*tid+1][10] = __log2f(sum);
        }
        if (i == HALO+1) {        // p == t0
            float sum = 0.f; float pr[10];
            #pragma unroll
            for (int s=0;s<10;++s) { pr[s] = a0s[s]*u[s]; sum += pr[s]; }
            #pragma unroll
            for (int s=0;s<10;++s) prl[2*tid][s] = pr[s];
            prl[2*tid][10] = __log2f(sum);
        }
        const bool keep = (p > TLEN-1);
        #pragma unroll
        for (int s=0;s<10;++s) {
            float gn = Elds[lre - i][s] * u[s];
            g[s] = keep ? g[s] : gn;
        }
    }
    __syncthreads();

    // ---- combine with LDS staging for coalesced output writes ----
    // stage = reused Elds region: 128 rows x 50 floats = 6400 <= 528*13 = 6864
    float* stage = &Elds[0][0];
    const int lg = tid & 7;
    const int tq = tid >> 3;                  // 0..31
    const int lb = lg * 7;                    // labels lb..lb+6 (masked at 50)
    float vO[10][7];
    #pragma unroll
    for (int s=0;s<10;++s)
        #pragma unroll
        for (int k=0;k<7;++k) vO[s][k] = Ol[s][lb+k];

    float* ob = out + ((size_t)b*TLEN + tb)*NLBL;   // 512 rows x 50 contiguous
    #pragma unroll 1
    for (int tile = 0; tile < 4; ++tile) {
        // compute 128 rows into stage
        #pragma unroll
        for (int j = 0; j < 4; ++j) {
            const int r = tq + 32*j;          // row within tile [0,128)
            const int t = tile*128 + r;       // row within block [0,512)
            float pv[10];
            #pragma unroll
            for (int s=0;s<10;++s) pv[s] = prl[t][s];
            const float ls = prl[t][10];
            #pragma unroll
            for (int k=0;k<7;++k) {
                float d = 0.f;
                #pragma unroll
                for (int s=0;s<10;++s) d = fmaf(pv[s], vO[s][k], d);
                float v = (__log2f(d) - ls) * LN2F;
                if (lb + k < NLBL) stage[r*NLBL + lb + k] = v;
            }
        }
        __syncthreads();
        // linear coalesced copy: 128*50 = 6400 dwords
        float* obt = ob + tile*128*NLBL;
        #pragma unroll
        for (int i = 0; i < 25; ++i) {
            const int d = tid + 256*i;
            obt[d] = stage[d];
        }
        __syncthreads();
    }
}

extern "C" void kernel_launch(void* const* d_in, const int* in_sizes, int n_in,
                              void* d_out, int out_size, void* d_ws, size_t ws_size,
                              hipStream_t stream) {
    const int*   sent  = (const int*)d_in[0];
    const float* W     = (const float*)d_in[1];
    const float* trans = (const float*)d_in[2];
    const float* outw  = (const float*)d_in[3];
    float* out = (float*)d_out;

    hipLaunchKernelGGL(k_all, dim3(BATCH * (TLEN / TPB)), dim3(256), 0, stream,
                       sent, W, trans, outw, out);
}

// Round 7
// 43.312 us; speedup vs baseline: 1.0048x; 1.0023x over previous
//
#include <hip/hip_runtime.h>

#define NST 10
#define NLBL 50
#define BATCH 256
#define TLEN 1024
#define TPB 512
#define HALO 8
#define ROWS (TPB + 2*HALO)   // 528
#define EPAD 13
#define PRPAD 13
#define SC 1.0e15f
#define LN2F 0.69314718055994531f

__global__ __launch_bounds__(256)
__attribute__((amdgpu_waves_per_eu(2, 2)))
void k_all(const int* __restrict__ sent,
           const float* __restrict__ W,
           const float* __restrict__ trans,
           const float* __restrict__ outw,
           float* __restrict__ out) {
    __shared__ alignas(16) float Elds[ROWS][EPAD];   // 27.5 KB (reused as combine stage)
    __shared__ alignas(16) float prl[TPB][PRPAD];    // 26.6 KB
    __shared__ alignas(16) float Tl[112];
    __shared__ alignas(16) float Ttl[112];
    __shared__ alignas(16) float Ol[NST][56];

    const int tid = threadIdx.x;
    const int b   = (int)blockIdx.x >> 1;
    const int tb  = ((int)blockIdx.x & 1) * TPB;

    // ---- parameter prep (redundant per block; cheap) ----
    if (tid < NST) {
        float r[NST]; float m = -1e30f, s = 0.f;
        #pragma unroll
        for (int j = 0; j < NST; ++j) { r[j] = trans[tid*NST + j]; m = fmaxf(m, r[j]); }
        #pragma unroll
        for (int j = 0; j < NST; ++j) { r[j] = __expf(r[j] - m); s += r[j]; }
        float inv = 1.f / s;
        #pragma unroll
        for (int j = 0; j < NST; ++j) { Tl[tid*NST + j] = r[j]*inv; Ttl[j*NST + tid] = r[j]*inv; }
    } else if (tid >= 32 && tid < 32 + NST) {
        const int i = tid - 32;
        float m = -1e30f, s = 0.f; float r[NLBL];
        for (int l = 0; l < NLBL; ++l) { r[l] = outw[i*NLBL + l]; m = fmaxf(m, r[l]); }
        for (int l = 0; l < NLBL; ++l) { r[l] = __expf(r[l] - m); s += r[l]; }
        float inv = 1.f / s;
        for (int l = 0; l < NLBL; ++l) Ol[i][l] = r[l]*inv;
        for (int l = NLBL; l < 56; ++l) Ol[i][l] = 0.f;
    }

    // ---- emission staging: gather W[tok], softmax, -> LDS ----
    const int* sb = sent + b*TLEN;
    for (int r = tid; r < ROWS; r += 256) {
        int p  = tb - HALO + r;
        int pc = min(max(p, 0), TLEN-1);
        int tok = sb[pc];
        const float2* w2 = reinterpret_cast<const float2*>(W + (size_t)tok*NST);
        float2 q0=w2[0], q1=w2[1], q2=w2[2], q3=w2[3], q4=w2[4];
        float e[10] = {q0.x,q0.y,q1.x,q1.y,q2.x,q2.y,q3.x,q3.y,q4.x,q4.y};
        float m = e[0];
        #pragma unroll
        for (int j=1;j<10;++j) m = fmaxf(m, e[j]);
        float s = 0.f;
        #pragma unroll
        for (int j=0;j<10;++j) { e[j] = __expf(e[j]-m); s += e[j]; }
        float inv = 1.f/s;
        #pragma unroll
        for (int j=0;j<10;++j) Elds[r][j] = e[j]*inv;
    }
    __syncthreads();

    const int t0  = tb + 2*tid;     // this thread's chunk = {t0, t0+1}
    const int lr0 = 2*tid;          // LDS row of global position t0-HALO

    float vT[100];
    #pragma unroll
    for (int k=0;k<100;++k) vT[k] = Tl[k];

    // ---- forward: steps from t0-HALO, keep alpha(t0), alpha(t0+1) ----
    float alpha[10], a0s[10], a1s[10];
    #pragma unroll
    for (int s=0;s<10;++s) alpha[s] = Elds[lr0][s] * SC;

    #pragma unroll
    for (int i=1;i<=HALO+1;++i) {
        const int p = t0 - HALO + i;
        float an[10];
        #pragma unroll
        for (int s=0;s<10;++s) {
            float acc = 0.f;
            #pragma unroll
            for (int j=0;j<10;++j) acc = fmaf(vT[s*10+j], alpha[j], acc);
            an[s] = acc * Elds[lr0+i][s];
        }
        const bool upd = (p >= 1);
        #pragma unroll
        for (int s=0;s<10;++s) alpha[s] = upd ? an[s] : alpha[s];
        if (i == HALO) {
            #pragma unroll
            for (int s=0;s<10;++s) a0s[s] = alpha[s];
        }
    }
    #pragma unroll
    for (int s=0;s<10;++s) a1s[s] = alpha[s];

    // ---- backward: steps from t0+HALO+1 down to t0; fuse posterior ----
    #pragma unroll
    for (int k=0;k<100;++k) vT[k] = Ttl[k];   // now holds T^T

    float g[10];
    const int lre = 2*tid + 2*HALO + 1;       // LDS row of t0+HALO+1 (clamped data)
    #pragma unroll
    for (int s=0;s<10;++s) g[s] = Elds[lre][s] * SC;

    #pragma unroll
    for (int i=1;i<=HALO+1;++i) {
        const int p = t0 + HALO + 1 - i;
        float u[10];
        #pragma unroll
        for (int s=0;s<10;++s) {
            float acc = 0.f;
            #pragma unroll
            for (int j=0;j<10;++j) acc = fmaf(vT[s*10+j], g[j], acc);
            u[s] = acc;
        }
        const bool last = (p == TLEN-1);
        #pragma unroll
        for (int s=0;s<10;++s) u[s] = last ? SC : u[s];
        if (i == HALO) {          // p == t0+1
            float sum = 0.f; float pr[10];
            #pragma unroll
            for (int s=0;s<10;++s) { pr[s] = a1s[s]*u[s]; sum += pr[s]; }
            #pragma unroll
            for (int s=0;s<10;++s) prl[2*tid+1][s] = pr[s];
            prl[2*tid+1][10] = __log2f(sum);
        }
        if (i == HALO+1) {        // p == t0
            float sum = 0.f; float pr[10];
            #pragma unroll
            for (int s=0;s<10;++s) { pr[s] = a0s[s]*u[s]; sum += pr[s]; }
            #pragma unroll
            for (int s=0;s<10;++s) prl[2*tid][s] = pr[s];
            prl[2*tid][10] = __log2f(sum);
        }
        const bool keep = (p > TLEN-1);
        #pragma unroll
        for (int s=0;s<10;++s) {
            float gn = Elds[lre - i][s] * u[s];
            g[s] = keep ? g[s] : gn;
        }
    }
    __syncthreads();

    // ---- combine with LDS staging for coalesced output writes ----
    // stage = reused Elds region: 128 rows x 50 floats = 6400 <= 528*13 = 6864
    float* stage = &Elds[0][0];
    const int lg = tid & 7;
    const int tq = tid >> 3;                  // 0..31
    const int lb = lg * 7;                    // labels lb..lb+6 (masked at 50)
    float vO[10][7];
    #pragma unroll
    for (int s=0;s<10;++s)
        #pragma unroll
        for (int k=0;k<7;++k) vO[s][k] = Ol[s][lb+k];

    float* ob = out + ((size_t)b*TLEN + tb)*NLBL;   // 512 rows x 50 contiguous
    #pragma unroll 1
    for (int tile = 0; tile < 4; ++tile) {
        // compute 128 rows into stage
        #pragma unroll
        for (int j = 0; j < 4; ++j) {
            const int r = tq + 32*j;          // row within tile [0,128)
            const int t = tile*128 + r;       // row within block [0,512)
            float pv[10];
            #pragma unroll
            for (int s=0;s<10;++s) pv[s] = prl[t][s];
            const float ls = prl[t][10];
            #pragma unroll
            for (int k=0;k<7;++k) {
                float d = 0.f;
                #pragma unroll
                for (int s=0;s<10;++s) d = fmaf(pv[s], vO[s][k], d);
                float v = (__log2f(d) - ls) * LN2F;
                if (lb + k < NLBL) stage[r*NLBL + lb + k] = v;
            }
        }
        __syncthreads();
        // linear coalesced copy: 128*50 = 6400 dwords
        float* obt = ob + tile*128*NLBL;
        #pragma unroll
        for (int i = 0; i < 25; ++i) {
            const int d = tid + 256*i;
            obt[d] = stage[d];
        }
        __syncthreads();
    }
}

extern "C" void kernel_launch(void* const* d_in, const int* in_sizes, int n_in,
                              void* d_out, int out_size, void* d_ws, size_t ws_size,
                              hipStream_t stream) {
    const int*   sent  = (const int*)d_in[0];
    const float* W     = (const float*)d_in[1];
    const float* trans = (const float*)d_in[2];
    const float* outw  = (const float*)d_in[3];
    float* out = (float*)d_out;

    hipLaunchKernelGGL(k_all, dim3(BATCH * (TLEN / TPB)), dim3(256), 0, stream,
                       sent, W, trans, outw, out);
}

// Round 8
// 31.248 us; speedup vs baseline: 1.3927x; 1.3860x over previous
//
#include <hip/hip_runtime.h>

#define NST 10
#define NLBL 50
#define BATCH 256
#define TLEN 1024
#define TPB 256
#define HALO 8
#define ROWS (TPB + 2*HALO)   // 272
#define EPAD 13
#define PRPAD 13
#define SC 1.0e15f
#define LN2F 0.69314718055994531f

static __device__ __forceinline__ float dppswap(float x) {
    // quad_perm [1,0,3,2]: lane 2k <-> 2k+1. Pure VALU, no LDS.
    return __int_as_float(__builtin_amdgcn_mov_dpp(__float_as_int(x), 0xB1, 0xF, 0xF, true));
}

__global__ __launch_bounds__(256, 4)
void k_all(const int* __restrict__ sent,
           const float* __restrict__ W,
           const float* __restrict__ trans,
           const float* __restrict__ outw,
           float* __restrict__ out) {
    __shared__ alignas(16) float Elds[ROWS][EPAD];   // 14.1 KB (reused as combine stage)
    __shared__ alignas(16) float prl[TPB][PRPAD];    // 13.3 KB
    __shared__ alignas(16) float Tl[112];
    __shared__ alignas(16) float Ttl[112];
    __shared__ alignas(16) float Ol[NST][56];

    const int tid = threadIdx.x;
    const int b   = (int)blockIdx.x >> 2;
    const int tb  = ((int)blockIdx.x & 3) * TPB;

    // ---- parameter prep (redundant per block; cheap) ----
    if (tid < NST) {
        float r[NST]; float m = -1e30f, s = 0.f;
        #pragma unroll
        for (int j = 0; j < NST; ++j) { r[j] = trans[tid*NST + j]; m = fmaxf(m, r[j]); }
        #pragma unroll
        for (int j = 0; j < NST; ++j) { r[j] = __expf(r[j] - m); s += r[j]; }
        float inv = 1.f / s;
        #pragma unroll
        for (int j = 0; j < NST; ++j) { Tl[tid*NST + j] = r[j]*inv; Ttl[j*NST + tid] = r[j]*inv; }
    } else if (tid >= 32 && tid < 32 + NST) {
        const int i = tid - 32;
        float m = -1e30f, s = 0.f; float r[NLBL];
        for (int l = 0; l < NLBL; ++l) { r[l] = outw[i*NLBL + l]; m = fmaxf(m, r[l]); }
        for (int l = 0; l < NLBL; ++l) { r[l] = __expf(r[l] - m); s += r[l]; }
        float inv = 1.f / s;
        for (int l = 0; l < NLBL; ++l) Ol[i][l] = r[l]*inv;
        for (int l = NLBL; l < 56; ++l) Ol[i][l] = 0.f;
    }

    // ---- emission staging: gather W[tok], softmax, -> LDS ----
    const int* sb = sent + b*TLEN;
    for (int r = tid; r < ROWS; r += 256) {
        int p  = tb - HALO + r;
        int pc = min(max(p, 0), TLEN-1);
        int tok = sb[pc];
        const float2* w2 = reinterpret_cast<const float2*>(W + (size_t)tok*NST);
        float2 q0=w2[0], q1=w2[1], q2=w2[2], q3=w2[3], q4=w2[4];
        float e[10] = {q0.x,q0.y,q1.x,q1.y,q2.x,q2.y,q3.x,q3.y,q4.x,q4.y};
        float m = e[0];
        #pragma unroll
        for (int j=1;j<10;++j) m = fmaxf(m, e[j]);
        float s = 0.f;
        #pragma unroll
        for (int j=0;j<10;++j) { e[j] = __expf(e[j]-m); s += e[j]; }
        float inv = 1.f/s;
        #pragma unroll
        for (int j=0;j<10;++j) Elds[r][j] = e[j]*inv;
    }
    __syncthreads();

    // ---- pair decomposition: lanes (2k,2k+1) share one 2-step chunk ----
    const int q   = tid & 1;          // 0: states 0..4, 1: states 5..9
    const int pr_ = tid >> 1;         // pair index 0..127
    const int j0  = 5*q;
    const int j1  = 5 - j0;           // partner's state base
    const int t0  = tb + 2*pr_;       // chunk = {t0, t0+1}
    const int lr0 = 2*pr_;            // LDS row of position t0-HALO
    const int lre = lr0 + 2*HALO + 1; // LDS row of position t0+HALO+1

    float Ta[5][5], Tb[5][5];
    #pragma unroll
    for (int r=0;r<5;++r)
        #pragma unroll
        for (int k=0;k<5;++k) {
            Ta[r][k] = Tl[(j0+r)*10 + j0 + k];
            Tb[r][k] = Tl[(j0+r)*10 + j1 + k];
        }

    // ---- forward: 9 steps from t0-HALO; save alpha(t0), alpha(t0+1) ----
    float m_[5], as0[5], as1[5];
    #pragma unroll
    for (int k=0;k<5;++k) m_[k] = Elds[lr0][j0+k] * SC;

    #pragma unroll
    for (int i=1;i<=HALO+1;++i) {
        const int p = t0 - HALO + i;
        float pp[5];
        #pragma unroll
        for (int k=0;k<5;++k) pp[k] = dppswap(m_[k]);
        float an[5];
        #pragma unroll
        for (int r=0;r<5;++r) {
            float acc = 0.f;
            #pragma unroll
            for (int k=0;k<5;++k) acc = fmaf(Ta[r][k], m_[k], acc);
            #pragma unroll
            for (int k=0;k<5;++k) acc = fmaf(Tb[r][k], pp[k], acc);
            an[r] = acc * Elds[lr0+i][j0+r];
        }
        const bool upd = (p >= 1);
        #pragma unroll
        for (int r=0;r<5;++r) m_[r] = upd ? an[r] : m_[r];
        if (i == HALO) {
            #pragma unroll
            for (int r=0;r<5;++r) as0[r] = m_[r];
        }
    }
    #pragma unroll
    for (int r=0;r<5;++r) as1[r] = m_[r];

    // ---- backward: 9 steps from t0+HALO+1 down to t0; fuse posterior ----
    #pragma unroll
    for (int r=0;r<5;++r)
        #pragma unroll
        for (int k=0;k<5;++k) {
            Ta[r][k] = Ttl[(j0+r)*10 + j0 + k];
            Tb[r][k] = Ttl[(j0+r)*10 + j1 + k];
        }

    const int pe = t0 + HALO + 1;
    float g_[5];
    #pragma unroll
    for (int k=0;k<5;++k) g_[k] = Elds[lre][j0+k] * SC;

    #pragma unroll
    for (int i=1;i<=HALO+1;++i) {
        const int p = pe - i;
        float pp[5];
        #pragma unroll
        for (int k=0;k<5;++k) pp[k] = dppswap(g_[k]);
        float u[5];
        #pragma unroll
        for (int r=0;r<5;++r) {
            float acc = 0.f;
            #pragma unroll
            for (int k=0;k<5;++k) acc = fmaf(Ta[r][k], g_[k], acc);
            #pragma unroll
            for (int k=0;k<5;++k) acc = fmaf(Tb[r][k], pp[k], acc);
            u[r] = acc;
        }
        const bool last = (p == TLEN-1);
        #pragma unroll
        for (int r=0;r<5;++r) u[r] = last ? SC : u[r];
        if (i == HALO) {          // p == t0+1
            float pv[5]; float sum = 0.f;
            #pragma unroll
            for (int r=0;r<5;++r) { pv[r] = as1[r]*u[r]; sum += pv[r]; }
            float full = sum + dppswap(sum);
            #pragma unroll
            for (int r=0;r<5;++r) prl[2*pr_+1][j0+r] = pv[r];
            prl[2*pr_+1][10] = __log2f(full);
        }
        if (i == HALO+1) {        // p == t0
            float pv[5]; float sum = 0.f;
            #pragma unroll
            for (int r=0;r<5;++r) { pv[r] = as0[r]*u[r]; sum += pv[r]; }
            float full = sum + dppswap(sum);
            #pragma unroll
            for (int r=0;r<5;++r) prl[2*pr_][j0+r] = pv[r];
            prl[2*pr_][10] = __log2f(full);
        }
        const bool keep = (p > TLEN-1);
        #pragma unroll
        for (int r=0;r<5;++r) {
            float gn = Elds[lre - i][j0+r] * u[r];
            g_[r] = keep ? g_[r] : gn;
        }
    }
    __syncthreads();

    // ---- combine with LDS staging for coalesced output writes ----
    // stage = reused Elds region: 64 rows x 50 = 3200 <= 272*13 = 3536
    float* stage = &Elds[0][0];
    const int lg = tid & 7;
    const int tq = tid >> 3;                  // 0..31
    const int lb = lg * 7;                    // labels lb..lb+6 (masked at 50)
    float vO[10][7];
    #pragma unroll
    for (int s=0;s<10;++s)
        #pragma unroll
        for (int k=0;k<7;++k) vO[s][k] = Ol[s][lb+k];

    float* ob = out + ((size_t)b*TLEN + tb)*NLBL;   // 256 rows x 50 contiguous
    #pragma unroll 1
    for (int tile = 0; tile < 4; ++tile) {
        #pragma unroll
        for (int j = 0; j < 2; ++j) {
            const int r = tq + 32*j;          // row within tile [0,64)
            const int t = tile*64 + r;        // row within block [0,256)
            float pv[10];
            #pragma unroll
            for (int s=0;s<10;++s) pv[s] = prl[t][s];
            const float ls = prl[t][10];
            #pragma unroll
            for (int k=0;k<7;++k) {
                float d = 0.f;
                #pragma unroll
                for (int s=0;s<10;++s) d = fmaf(pv[s], vO[s][k], d);
                float v = (__log2f(d) - ls) * LN2F;
                if (lb + k < NLBL) stage[r*NLBL + lb + k] = v;
            }
        }
        __syncthreads();
        // linear coalesced copy: 64*50 = 3200 dwords
        float* obt = ob + tile*64*NLBL;
        #pragma unroll
        for (int i = 0; i < 13; ++i) {
            const int d = tid + 256*i;
            if (d < 64*NLBL) obt[d] = stage[d];
        }
        __syncthreads();
    }
}

extern "C" void kernel_launch(void* const* d_in, const int* in_sizes, int n_in,
                              void* d_out, int out_size, void* d_ws, size_t ws_size,
                              hipStream_t stream) {
    const int*   sent  = (const int*)d_in[0];
    const float* W     = (const float*)d_in[1];
    const float* trans = (const float*)d_in[2];
    const float* outw  = (const float*)d_in[3];
    float* out = (float*)d_out;

    hipLaunchKernelGGL(k_all, dim3(BATCH * (TLEN / TPB)), dim3(256), 0, stream,
                       sent, W, trans, outw, out);
}